// Round 5
// baseline (514.814 us; speedup 1.0000x reference)
//
#include <hip/hip_runtime.h>
#include <math.h>

#define B_IMG 16
#define P_N   2048
#define PAIR_CAP 98304   // per-image u32 pair entries (6 MB pool total)

constexpr float SCORE_T = 0.05f;
constexpr float NMS_T   = 0.5f;
constexpr float XCLIP   = 4.135166556742356f; // log(1000/16)
constexpr float IMW     = 1333.0f;
constexpr float IMH     = 800.0f;

// monotone float->uint mapping (ascending float order, incl +inf)
__device__ __forceinline__ unsigned int fkey(float f) {
    unsigned int u = __float_as_uint(f);
    return (u & 0x80000000u) ? ~u : (u | 0x80000000u);
}

// ---------------------------------------------------------------------------
// K1: decode + score + sort-key per row; zero pair counters
// ---------------------------------------------------------------------------
__global__ __launch_bounds__(256) void decode_kernel(
    const float* __restrict__ cls, const float* __restrict__ codes,
    const float* __restrict__ props, float4* __restrict__ boxes4,
    float* __restrict__ scores, unsigned int* __restrict__ keys,
    unsigned int* __restrict__ paircnt)
{
#pragma clang fp contract(off)
    if (blockIdx.x == 0 && threadIdx.x < B_IMG) paircnt[threadIdx.x] = 0;
    const int gid = blockIdx.x * 256 + threadIdx.x;   // 0..32767

    float2 lg = reinterpret_cast<const float2*>(cls)[gid];
    float score = 1.0f / (1.0f + expf(lg.x - lg.y));

    float4 pb = reinterpret_cast<const float4*>(props)[gid];
    float4 c  = reinterpret_cast<const float4*>(codes)[gid * 2 + 1];

    float w  = pb.z - pb.x + 1.0f;
    float h  = pb.w - pb.y + 1.0f;
    float cx = pb.x + 0.5f * w;
    float cy = pb.y + 0.5f * h;

    float dx = c.x / 10.0f;
    float dy = c.y / 10.0f;
    float dw = fminf(c.z / 5.0f, XCLIP);
    float dh = fminf(c.w / 5.0f, XCLIP);

    float pcx = dx * w + cx;
    float pcy = dy * h + cy;
    float pw  = expf(dw) * w;
    float ph  = expf(dh) * h;

    float x1 = pcx - 0.5f * pw;
    float y1 = pcy - 0.5f * ph;
    float x2 = (pcx + 0.5f * pw) - 1.0f;
    float y2 = (pcy + 0.5f * ph) - 1.0f;

    x1 = fminf(fmaxf(x1, 0.0f), IMW - 1.0f);
    y1 = fminf(fmaxf(y1, 0.0f), IMH - 1.0f);
    x2 = fminf(fmaxf(x2, 0.0f), IMW - 1.0f);
    y2 = fminf(fmaxf(y2, 0.0f), IMH - 1.0f);

    boxes4[gid] = make_float4(x1, y1, x2, y2);
    scores[gid] = score;
    float keyf = (score > SCORE_T) ? -score : __int_as_float(0x7f800000); // +inf
    keys[gid] = fkey(keyf);
}

// ---------------------------------------------------------------------------
// K2: stable rank by counting (replaces bitonic sort) + scatter sorted rows
//   rank_i = #{ j : key_j < key_i  ||  (key_j == key_i && j < i) }
// ---------------------------------------------------------------------------
__global__ __launch_bounds__(512) void rank_kernel(
    const float4* __restrict__ boxes4, const float* __restrict__ scores,
    const unsigned int* __restrict__ keys, float* __restrict__ out)
{
    __shared__ unsigned int sk[P_N];
    __shared__ unsigned short pc[512];
    const int img = blockIdx.x >> 5;   // 32 blocks per image
    const int blk = blockIdx.x & 31;   // 64 rows per block
    const int tid = threadIdx.x;
    const unsigned int* kb = keys + img * P_N;

    for (int t = tid; t < P_N; t += 512) sk[t] = kb[t];
    __syncthreads();

    const int il = tid >> 3, sub = tid & 7;      // 8 threads per row
    const int i  = blk * 64 + il;
    const unsigned int ki = sk[i];
    int cnt = 0;
    // j partition: sub handles j == sub (mod 8); il-rotation spreads banks
    for (int t = 0; t < 256; ++t) {
        int j = sub + 8 * ((t + il) & 255);
        unsigned int kj = sk[j];
        cnt += (kj < ki) || (kj == ki && j < i);
    }
    pc[tid] = (unsigned short)cnt;
    __syncthreads();

    if (tid < 64) {
        const int i2 = blk * 64 + tid;
        int r = 0;
#pragma unroll
        for (int s = 0; s < 8; ++s) r += pc[tid * 8 + s];
        float4 b = boxes4[img * P_N + i2];
        float  s = scores[img * P_N + i2];
        float* o = out + ((size_t)img * P_N + r) * 5;
        o[0] = b.x; o[1] = b.y; o[2] = b.z; o[3] = b.w; o[4] = s;
    }
}

// ---------------------------------------------------------------------------
// K3: sparse suppression-pair extraction.  pair = (i<<12)|j, i<j, iou>0.5
// ---------------------------------------------------------------------------
__global__ __launch_bounds__(256) void pair_kernel(
    const float* __restrict__ out, unsigned int* __restrict__ paircnt,
    unsigned int* __restrict__ pool)
{
#pragma clang fp contract(off)
    __shared__ float4 sb[P_N];
    __shared__ float  sa[P_N];
    const int img = blockIdx.x >> 7;          // 128 blocks per image
    const int sub = blockIdx.x & 127;
    const int jt  = sub >> 2;                 // j-tile (32)
    const int ic  = sub & 3;                  // i-chunk (4)
    const int tid = threadIdx.x;
    const int w = tid >> 6, lane = tid & 63;

    const int nrows = jt * 64 + 64;
    for (int r = tid; r < nrows; r += 256) {
        const float* o = out + ((size_t)img * P_N + r) * 5;
        float4 b = make_float4(o[0], o[1], o[2], o[3]);
        sb[r] = b;
        sa[r] = (b.z - b.x) * (b.w - b.y);
    }
    __syncthreads();

    const int j = jt * 64 + lane;
    const float4 bj = sb[j];
    const float  aj = sa[j];
    unsigned int* mypool = pool + (size_t)img * PAIR_CAP;

    for (int i = ic * 4 + w; i < j; i += 16) {
        float4 bi = sb[i];
        float  ai = sa[i];
        float ltx = fmaxf(bi.x, bj.x);
        float lty = fmaxf(bi.y, bj.y);
        float rbx = fminf(bi.z, bj.z);
        float rby = fminf(bi.w, bj.w);
        float wx = fmaxf(rbx - ltx, 0.0f);
        float wy = fmaxf(rby - lty, 0.0f);
        float inter = wx * wy;
        float denom = ((ai + aj) - inter) + 1e-9f;
        bool sup = (inter / denom) > NMS_T;   // exact reference comparison
        if (sup) {
            unsigned int idx = atomicAdd(&paircnt[img], 1u);
            if (idx < PAIR_CAP)
                mypool[idx] = ((unsigned int)i << 12) | (unsigned int)j;
        }
    }
}

// ---------------------------------------------------------------------------
// K4: fixpoint iteration of k = valid & ~(sup from kept earlier); zero rows.
//   Greedy NMS is the unique fixpoint (triangular i<j edges). Converges in
//   <= longest-chain iterations; detected via change flag.
// ---------------------------------------------------------------------------
__global__ __launch_bounds__(1024) void fixpoint_kernel(
    float* __restrict__ out, const unsigned int* __restrict__ paircnt,
    const unsigned int* __restrict__ pool)
{
#pragma clang fp contract(off)
    __shared__ float4 sb[P_N];            // dense-fallback staging
    __shared__ unsigned int kw[64], vw[64], supw[64];
    __shared__ int flag;
    const int img = blockIdx.x, tid = threadIdx.x;
    const int lane = tid & 63, wv = tid >> 6;
    const unsigned int cnt = paircnt[img];

    if (cnt <= PAIR_CAP) {
        // ---- sparse fixpoint path ----
        bool v0 = out[((size_t)img * P_N + tid) * 5 + 4] > SCORE_T;
        bool v1 = out[((size_t)img * P_N + tid + 1024) * 5 + 4] > SCORE_T;
        unsigned long long b0 = __ballot(v0), b1 = __ballot(v1);
        if (lane == 0) {
            vw[wv * 2]          = (unsigned int)b0;
            vw[wv * 2 + 1]      = (unsigned int)(b0 >> 32);
            vw[32 + wv * 2]     = (unsigned int)b1;
            vw[32 + wv * 2 + 1] = (unsigned int)(b1 >> 32);
        }
        __syncthreads();
        if (tid < 64) kw[tid] = vw[tid];
        __syncthreads();

        const unsigned int* mypool = pool + (size_t)img * PAIR_CAP;
        for (;;) {
            if (tid < 64) supw[tid] = 0;
            if (tid == 0) flag = 0;
            __syncthreads();
            for (unsigned int p = tid; p < cnt; p += 1024) {
                unsigned int pr = mypool[p];
                unsigned int i = pr >> 12, j = pr & 0xFFFu;
                if ((kw[i >> 5] >> (i & 31)) & 1u)
                    atomicOr(&supw[j >> 5], 1u << (j & 31));
            }
            __syncthreads();
            if (tid < 64) {
                unsigned int nk = vw[tid] & ~supw[tid];
                if (nk != kw[tid]) { kw[tid] = nk; flag = 1; }
            }
            __syncthreads();
            int f = flag;
            __syncthreads();
            if (!f) break;
        }

        // zero non-kept rows (each thread owns rows tid and tid+1024)
        for (int h = 0; h < 2; ++h) {
            int r = tid + h * 1024;
            if (!((kw[r >> 5] >> (r & 31)) & 1u)) {
                float* o = out + ((size_t)img * P_N + r) * 5;
                o[0] = 0.0f; o[1] = 0.0f; o[2] = 0.0f; o[3] = 0.0f; o[4] = 0.0f;
            }
        }
    } else {
        // ---- dense fallback: on-the-fly serial cascade on wave 0 ----
        for (int h = 0; h < 2; ++h) {
            int r = tid + h * 1024;
            const float* o = out + ((size_t)img * P_N + r) * 5;
            sb[r] = make_float4(o[0], o[1], o[2], o[3]);
        }
        __syncthreads();
        if (wv == 0) {
            unsigned int keep = 0;
            for (int b = 0; b < 32; ++b) {
                int p = lane * 32 + b;
                if (out[((size_t)img * P_N + p) * 5 + 4] > SCORE_T)
                    keep |= (1u << b);
            }
            for (int i = 0; i < P_N; ++i) {
                unsigned int kwd =
                    (unsigned int)__builtin_amdgcn_readlane((int)keep, i >> 5);
                if ((kwd >> (i & 31)) & 1u) {
                    float4 bi = sb[i];
                    float area_i = (bi.z - bi.x) * (bi.w - bi.y);
                    unsigned int m = 0;
                    for (int b = 0; b < 32; ++b) {
                        int jj = lane * 32 + b;
                        if (jj > i) {
                            float4 bj = sb[jj];
                            float area_j = (bj.z - bj.x) * (bj.w - bj.y);
                            float ltx = fmaxf(bi.x, bj.x);
                            float lty = fmaxf(bi.y, bj.y);
                            float rbx = fminf(bi.z, bj.z);
                            float rby = fminf(bi.w, bj.w);
                            float wx = fmaxf(rbx - ltx, 0.0f);
                            float wy = fmaxf(rby - lty, 0.0f);
                            float inter = wx * wy;
                            float denom = ((area_i + area_j) - inter) + 1e-9f;
                            if ((inter / denom) > NMS_T) m |= (1u << b);
                        }
                    }
                    keep &= ~m;
                }
            }
            for (int b = 0; b < 32; ++b) {
                if (!((keep >> b) & 1u)) {
                    int p = lane * 32 + b;
                    float* o = out + ((size_t)img * P_N + p) * 5;
                    o[0] = 0.0f; o[1] = 0.0f; o[2] = 0.0f; o[3] = 0.0f; o[4] = 0.0f;
                }
            }
        }
    }
}

// ---------------------------------------------------------------------------
// ws-too-small fallback pair (validated in rounds 1-3): bitonic sort + serial
// ---------------------------------------------------------------------------
__global__ __launch_bounds__(1024) void prep_sort_kernel(
    const float* __restrict__ cls, const float* __restrict__ codes,
    const float* __restrict__ props, float* __restrict__ out)
{
#pragma clang fp contract(off)
    __shared__ float4 sbox[P_N];
    __shared__ float  ssc[P_N];
    __shared__ unsigned long long skey[P_N];
    const int img = blockIdx.x;
    const int tid = threadIdx.x;

    for (int p = tid; p < P_N; p += 1024) {
        float2 lg = reinterpret_cast<const float2*>(cls)[img * P_N + p];
        float score = 1.0f / (1.0f + expf(lg.x - lg.y));
        float4 pb = reinterpret_cast<const float4*>(props)[img * P_N + p];
        float4 c  = reinterpret_cast<const float4*>(codes)[(img * P_N + p) * 2 + 1];
        float w  = pb.z - pb.x + 1.0f;
        float h  = pb.w - pb.y + 1.0f;
        float cx = pb.x + 0.5f * w;
        float cy = pb.y + 0.5f * h;
        float dx = c.x / 10.0f;
        float dy = c.y / 10.0f;
        float dw = fminf(c.z / 5.0f, XCLIP);
        float dh = fminf(c.w / 5.0f, XCLIP);
        float pcx = dx * w + cx;
        float pcy = dy * h + cy;
        float pw  = expf(dw) * w;
        float ph  = expf(dh) * h;
        float x1 = pcx - 0.5f * pw;
        float y1 = pcy - 0.5f * ph;
        float x2 = (pcx + 0.5f * pw) - 1.0f;
        float y2 = (pcy + 0.5f * ph) - 1.0f;
        x1 = fminf(fmaxf(x1, 0.0f), IMW - 1.0f);
        y1 = fminf(fmaxf(y1, 0.0f), IMH - 1.0f);
        x2 = fminf(fmaxf(x2, 0.0f), IMW - 1.0f);
        y2 = fminf(fmaxf(y2, 0.0f), IMH - 1.0f);
        sbox[p] = make_float4(x1, y1, x2, y2);
        ssc[p]  = score;
        float key = (score > SCORE_T) ? -score : __int_as_float(0x7f800000);
        skey[p] = (((unsigned long long)fkey(key)) << 32) | (unsigned int)p;
    }
    __syncthreads();
    for (int k = 2; k <= P_N; k <<= 1) {
        for (int j = k >> 1; j > 0; j >>= 1) {
            for (int t = tid; t < P_N; t += 1024) {
                int ixj = t ^ j;
                if (ixj > t) {
                    unsigned long long a = skey[t], b = skey[ixj];
                    bool up = ((t & k) == 0);
                    if ((a > b) == up) { skey[t] = b; skey[ixj] = a; }
                }
            }
            __syncthreads();
        }
    }
    for (int e = tid; e < P_N; e += 1024) {
        unsigned long long kv = skey[e];
        int idx = (int)(kv & 0xFFFFFFFFull);
        float4 b4 = sbox[idx];
        float  s  = ssc[idx];
        float* o = out + ((size_t)img * P_N + e) * 5;
        o[0] = b4.x; o[1] = b4.y; o[2] = b4.z; o[3] = b4.w; o[4] = s;
    }
}

__global__ __launch_bounds__(64) void nms_fallback(float* __restrict__ out)
{
#pragma clang fp contract(off)
    __shared__ float4 sb[P_N];
    const int img  = blockIdx.x;
    const int lane = threadIdx.x;
    unsigned int keep = 0;
    for (int b = 0; b < 32; ++b) {
        int p = lane * 32 + b;
        const float* o = out + ((size_t)img * P_N + p) * 5;
        sb[p] = make_float4(o[0], o[1], o[2], o[3]);
        if (o[4] > SCORE_T) keep |= (1u << b);
    }
    __syncthreads();
    for (int i = 0; i < P_N; ++i) {
        unsigned int kw =
            (unsigned int)__builtin_amdgcn_readlane((int)keep, i >> 5);
        if ((kw >> (i & 31)) & 1u) {
            float4 bi = sb[i];
            float area_i = (bi.z - bi.x) * (bi.w - bi.y);
            unsigned int m = 0;
            for (int b = 0; b < 32; ++b) {
                int j = lane * 32 + b;
                if (j > i) {
                    float4 bj = sb[j];
                    float area_j = (bj.z - bj.x) * (bj.w - bj.y);
                    float ltx = fmaxf(bi.x, bj.x);
                    float lty = fmaxf(bi.y, bj.y);
                    float rbx = fminf(bi.z, bj.z);
                    float rby = fminf(bi.w, bj.w);
                    float wx = fmaxf(rbx - ltx, 0.0f);
                    float wy = fmaxf(rby - lty, 0.0f);
                    float inter = wx * wy;
                    float denom = ((area_i + area_j) - inter) + 1e-9f;
                    if ((inter / denom) > NMS_T) m |= (1u << b);
                }
            }
            keep &= ~m;
        }
    }
    for (int b = 0; b < 32; ++b) {
        if (!((keep >> b) & 1u)) {
            int p = lane * 32 + b;
            float* o = out + ((size_t)img * P_N + p) * 5;
            o[0] = 0.0f; o[1] = 0.0f; o[2] = 0.0f; o[3] = 0.0f; o[4] = 0.0f;
        }
    }
}

// ---------------------------------------------------------------------------
extern "C" void kernel_launch(void* const* d_in, const int* in_sizes, int n_in,
                              void* d_out, int out_size, void* d_ws, size_t ws_size,
                              hipStream_t stream) {
    const float* cls   = (const float*)d_in[0];
    const float* codes = (const float*)d_in[1];
    const float* props = (const float*)d_in[2];
    float* out = (float*)d_out;

    // ws layout
    const size_t off_boxes  = 0;                                   // 512 KB
    const size_t off_scores = off_boxes  + (size_t)B_IMG * P_N * 16;
    const size_t off_keys   = off_scores + (size_t)B_IMG * P_N * 4;
    const size_t off_cnt    = off_keys   + (size_t)B_IMG * P_N * 4;
    const size_t off_pool   = off_cnt    + 1024;
    const size_t total      = off_pool + (size_t)B_IMG * PAIR_CAP * 4;

    if (ws_size >= total) {
        float4*       boxes4  = (float4*)((char*)d_ws + off_boxes);
        float*        scores  = (float*)((char*)d_ws + off_scores);
        unsigned int* keys    = (unsigned int*)((char*)d_ws + off_keys);
        unsigned int* paircnt = (unsigned int*)((char*)d_ws + off_cnt);
        unsigned int* pool    = (unsigned int*)((char*)d_ws + off_pool);

        decode_kernel<<<(B_IMG * P_N) / 256, 256, 0, stream>>>(
            cls, codes, props, boxes4, scores, keys, paircnt);
        rank_kernel<<<B_IMG * 32, 512, 0, stream>>>(boxes4, scores, keys, out);
        pair_kernel<<<B_IMG * 128, 256, 0, stream>>>(out, paircnt, pool);
        fixpoint_kernel<<<B_IMG, 1024, 0, stream>>>(out, paircnt, pool);
    } else {
        prep_sort_kernel<<<B_IMG, 1024, 0, stream>>>(cls, codes, props, out);
        nms_fallback<<<B_IMG, 64, 0, stream>>>(out);
    }
}

// Round 6
// 106.363 us; speedup vs baseline: 4.8402x; 4.8402x over previous
//
#include <hip/hip_runtime.h>
#include <math.h>

#define B_IMG 16
#define P_N   2048
#define IMG_TM_U32 67584   // per-image triangular mask u32 words (33792 u64)

constexpr float SCORE_T = 0.05f;
constexpr float NMS_T   = 0.5f;
constexpr float XCLIP   = 4.135166556742356f; // log(1000/16)
constexpr float IMW     = 1333.0f;
constexpr float IMH     = 800.0f;

// monotone float->uint mapping (ascending float order, incl +inf)
__device__ __forceinline__ unsigned int fkey(float f) {
    unsigned int u = __float_as_uint(f);
    return (u & 0x80000000u) ? ~u : (u | 0x80000000u);
}

// u32 word offset of row j's mask within an image (rows are compact triangular)
__device__ __forceinline__ unsigned int tm_base(int j) {
    int b = j >> 6, r = j & 63;
    return 2u * (unsigned)(b + 1) * (unsigned)(32 * b + r);
}

// ---------------------------------------------------------------------------
// K1: decode + score + sort-key per row
// ---------------------------------------------------------------------------
__global__ __launch_bounds__(256) void decode_kernel(
    const float* __restrict__ cls, const float* __restrict__ codes,
    const float* __restrict__ props, float4* __restrict__ boxes4,
    float* __restrict__ scores, unsigned int* __restrict__ keys)
{
#pragma clang fp contract(off)
    const int gid = blockIdx.x * 256 + threadIdx.x;   // 0..32767

    float2 lg = reinterpret_cast<const float2*>(cls)[gid];
    float score = 1.0f / (1.0f + expf(lg.x - lg.y));

    float4 pb = reinterpret_cast<const float4*>(props)[gid];
    float4 c  = reinterpret_cast<const float4*>(codes)[gid * 2 + 1];

    float w  = pb.z - pb.x + 1.0f;
    float h  = pb.w - pb.y + 1.0f;
    float cx = pb.x + 0.5f * w;
    float cy = pb.y + 0.5f * h;

    float dx = c.x / 10.0f;
    float dy = c.y / 10.0f;
    float dw = fminf(c.z / 5.0f, XCLIP);
    float dh = fminf(c.w / 5.0f, XCLIP);

    float pcx = dx * w + cx;
    float pcy = dy * h + cy;
    float pw  = expf(dw) * w;
    float ph  = expf(dh) * h;

    float x1 = pcx - 0.5f * pw;
    float y1 = pcy - 0.5f * ph;
    float x2 = (pcx + 0.5f * pw) - 1.0f;
    float y2 = (pcy + 0.5f * ph) - 1.0f;

    x1 = fminf(fmaxf(x1, 0.0f), IMW - 1.0f);
    y1 = fminf(fmaxf(y1, 0.0f), IMH - 1.0f);
    x2 = fminf(fmaxf(x2, 0.0f), IMW - 1.0f);
    y2 = fminf(fmaxf(y2, 0.0f), IMH - 1.0f);

    boxes4[gid] = make_float4(x1, y1, x2, y2);
    scores[gid] = score;
    float keyf = (score > SCORE_T) ? -score : __int_as_float(0x7f800000); // +inf
    keys[gid] = fkey(keyf);
}

// ---------------------------------------------------------------------------
// K2: stable rank by counting + scatter sorted rows (validated round 5)
// ---------------------------------------------------------------------------
__global__ __launch_bounds__(512) void rank_kernel(
    const float4* __restrict__ boxes4, const float* __restrict__ scores,
    const unsigned int* __restrict__ keys, float* __restrict__ out)
{
    __shared__ unsigned int sk[P_N];
    __shared__ unsigned short pc[512];
    const int img = blockIdx.x >> 5;   // 32 blocks per image
    const int blk = blockIdx.x & 31;   // 64 rows per block
    const int tid = threadIdx.x;
    const unsigned int* kb = keys + img * P_N;

    for (int t = tid; t < P_N; t += 512) sk[t] = kb[t];
    __syncthreads();

    const int il = tid >> 3, sub = tid & 7;      // 8 threads per row
    const int i  = blk * 64 + il;
    const unsigned int ki = sk[i];
    int cnt = 0;
    for (int t = 0; t < 256; ++t) {
        int j = sub + 8 * ((t + il) & 255);
        unsigned int kj = sk[j];
        cnt += (kj < ki) || (kj == ki && j < i);
    }
    pc[tid] = (unsigned short)cnt;
    __syncthreads();

    if (tid < 64) {
        const int i2 = blk * 64 + tid;
        int r = 0;
#pragma unroll
        for (int s = 0; s < 8; ++s) r += pc[tid * 8 + s];
        float4 b = boxes4[img * P_N + i2];
        float  s = scores[img * P_N + i2];
        float* o = out + ((size_t)img * P_N + r) * 5;
        o[0] = b.x; o[1] = b.y; o[2] = b.z; o[3] = b.w; o[4] = s;
    }
}

// ---------------------------------------------------------------------------
// K3: dense triangular transposed mask.  Row j (sorted order), bit i (i<j):
//   word w (u32) of row j covers i = w*32..w*32+31;  sup = IoU > 0.5
//   One wave per row; ballot-packed; coalesced 4B stores, no atomics.
// ---------------------------------------------------------------------------
__global__ __launch_bounds__(512) void tmask_kernel(
    const float* __restrict__ out, unsigned int* __restrict__ tmask)
{
#pragma clang fp contract(off)
    __shared__ float4 sb[P_N];
    __shared__ float  sa[P_N];
    const int img = blockIdx.x >> 8;     // 256 blocks per image
    const int rb  = blockIdx.x & 255;    // 8 rows per block
    const int tid = threadIdx.x;

    const int nrows = rb * 8 + 8;        // need i < max j of this block
    for (int r = tid; r < nrows; r += 512) {
        const float* o = out + ((size_t)img * P_N + r) * 5;
        float4 b = make_float4(o[0], o[1], o[2], o[3]);
        sb[r] = b;
        sa[r] = (b.z - b.x) * (b.w - b.y);
    }
    __syncthreads();

    const int wv = tid >> 6, lane = tid & 63;
    const int j  = rb * 8 + wv;
    const int bj = j >> 6;

    const float4 bjx = sb[j];
    const float  aj  = sa[j];

    unsigned int myword = 0;
    for (int w = 0; w <= bj; ++w) {
        int i = w * 64 + lane;
        bool sup = false;
        if (i < j) {
            float4 bi = sb[i];
            float ai  = sa[i];
            float ltx = fmaxf(bi.x, bjx.x);
            float lty = fmaxf(bi.y, bjx.y);
            float rbx = fminf(bi.z, bjx.z);
            float rby = fminf(bi.w, bjx.w);
            float wx = fmaxf(rbx - ltx, 0.0f);
            float wy = fmaxf(rby - lty, 0.0f);
            float inter = wx * wy;
            float denom = ((ai + aj) - inter) + 1e-9f;
            sup = (inter / denom) > NMS_T;   // exact reference comparison
        }
        unsigned long long m = __ballot(sup);
        if ((lane >> 1) == w)
            myword = (lane & 1) ? (unsigned int)(m >> 32) : (unsigned int)m;
    }
    if (lane < 2 * (bj + 1))
        tmask[(size_t)img * IMG_TM_U32 + tm_base(j) + lane] = myword;
}

// ---------------------------------------------------------------------------
// K4: Jacobi fixpoint of  k[j] = valid[j] & ~OR_{i<j,sup(i,j)} k[i]
//   (unique fixpoint == greedy NMS).  16 blocks x 512 thr; mask rows live in
//   registers (4 rows/thread, constant 132 u32 each); keep vector in LDS.
// ---------------------------------------------------------------------------
__global__ __launch_bounds__(512) void fixpoint_kernel(
    float* __restrict__ out, const unsigned int* __restrict__ tmask)
{
    __shared__ unsigned int kw[64];
    __shared__ int flag;
    const int img = blockIdx.x;
    const int tid = threadIdx.x;
    const int wv = tid >> 6, lane = tid & 63;

    // 4 row-groups per wave: sizes balance to 132 u32/thread total
    const int g1 = wv, g2 = 15 - wv, g3 = 16 + wv, g4 = 31 - wv;
    const int j1 = g1 * 64 + lane, j2 = g2 * 64 + lane,
              j3 = g3 * 64 + lane, j4 = g4 * 64 + lane;
    const int n1 = 2 * (g1 + 1), n2 = 2 * (g2 + 1),
              n3 = 2 * (g3 + 1), n4 = 2 * (g4 + 1);

    const unsigned int* tmi = tmask + (size_t)img * IMG_TM_U32;
    unsigned int m1[16], m2[32], m3[48], m4[64];
    {
        const unsigned int* p1 = tmi + tm_base(j1);
#pragma unroll
        for (int w = 0; w < 16; ++w) m1[w] = (w < n1) ? p1[w] : 0u;
        const unsigned int* p2 = tmi + tm_base(j2);
#pragma unroll
        for (int w = 0; w < 32; ++w) m2[w] = (w < n2) ? p2[w] : 0u;
        const unsigned int* p3 = tmi + tm_base(j3);
#pragma unroll
        for (int w = 0; w < 48; ++w) m3[w] = (w < n3) ? p3[w] : 0u;
        const unsigned int* p4 = tmi + tm_base(j4);
#pragma unroll
        for (int w = 0; w < 64; ++w) m4[w] = (w < n4) ? p4[w] : 0u;
    }

    const bool v1 = out[((size_t)img * P_N + j1) * 5 + 4] > SCORE_T;
    const bool v2 = out[((size_t)img * P_N + j2) * 5 + 4] > SCORE_T;
    const bool v3 = out[((size_t)img * P_N + j3) * 5 + 4] > SCORE_T;
    const bool v4 = out[((size_t)img * P_N + j4) * 5 + 4] > SCORE_T;
    bool k1 = v1, k2 = v2, k3 = v3, k4 = v4;

    auto publish = [&](bool a, bool b, bool c, bool d) {
        unsigned long long t;
        t = __ballot(a);
        if (lane == 0) { kw[2*g1] = (unsigned int)t; kw[2*g1+1] = (unsigned int)(t>>32); }
        t = __ballot(b);
        if (lane == 0) { kw[2*g2] = (unsigned int)t; kw[2*g2+1] = (unsigned int)(t>>32); }
        t = __ballot(c);
        if (lane == 0) { kw[2*g3] = (unsigned int)t; kw[2*g3+1] = (unsigned int)(t>>32); }
        t = __ballot(d);
        if (lane == 0) { kw[2*g4] = (unsigned int)t; kw[2*g4+1] = (unsigned int)(t>>32); }
    };

    publish(k1, k2, k3, k4);
    __syncthreads();

    for (;;) {
        unsigned int s1 = 0, s2 = 0, s3 = 0, s4 = 0;
#pragma unroll
        for (int w = 0; w < 16; ++w) s1 |= m1[w] & kw[w];
#pragma unroll
        for (int w = 0; w < 32; ++w) s2 |= m2[w] & kw[w];
#pragma unroll
        for (int w = 0; w < 48; ++w) s3 |= m3[w] & kw[w];
#pragma unroll
        for (int w = 0; w < 64; ++w) s4 |= m4[w] & kw[w];
        bool nk1 = v1 && !s1, nk2 = v2 && !s2, nk3 = v3 && !s3, nk4 = v4 && !s4;
        bool ch = (nk1 != k1) | (nk2 != k2) | (nk3 != k3) | (nk4 != k4);

        __syncthreads();                 // (1) all kw reads done
        if (tid == 0) flag = 0;
        __syncthreads();                 // (2) reset visible
        publish(nk1, nk2, nk3, nk4);
        if (__builtin_amdgcn_ballot_w64(ch) != 0 && lane == 0) flag = 1;
        k1 = nk1; k2 = nk2; k3 = nk3; k4 = nk4;
        __syncthreads();                 // (3) new kw + flag visible
        if (!flag) break;
    }

    // zero non-kept rows
    auto zero_row = [&](int j, bool k) {
        if (!k) {
            float* o = out + ((size_t)img * P_N + j) * 5;
            o[0] = 0.0f; o[1] = 0.0f; o[2] = 0.0f; o[3] = 0.0f; o[4] = 0.0f;
        }
    };
    zero_row(j1, k1); zero_row(j2, k2); zero_row(j3, k3); zero_row(j4, k4);
}

// ---------------------------------------------------------------------------
// ws-too-small fallback (validated rounds 1-4): bitonic sort + serial cascade
// ---------------------------------------------------------------------------
__global__ __launch_bounds__(1024) void prep_sort_kernel(
    const float* __restrict__ cls, const float* __restrict__ codes,
    const float* __restrict__ props, float* __restrict__ out)
{
#pragma clang fp contract(off)
    __shared__ float4 sbox[P_N];
    __shared__ float  ssc[P_N];
    __shared__ unsigned long long skey[P_N];
    const int img = blockIdx.x;
    const int tid = threadIdx.x;

    for (int p = tid; p < P_N; p += 1024) {
        float2 lg = reinterpret_cast<const float2*>(cls)[img * P_N + p];
        float score = 1.0f / (1.0f + expf(lg.x - lg.y));
        float4 pb = reinterpret_cast<const float4*>(props)[img * P_N + p];
        float4 c  = reinterpret_cast<const float4*>(codes)[(img * P_N + p) * 2 + 1];
        float w  = pb.z - pb.x + 1.0f;
        float h  = pb.w - pb.y + 1.0f;
        float cx = pb.x + 0.5f * w;
        float cy = pb.y + 0.5f * h;
        float dx = c.x / 10.0f;
        float dy = c.y / 10.0f;
        float dw = fminf(c.z / 5.0f, XCLIP);
        float dh = fminf(c.w / 5.0f, XCLIP);
        float pcx = dx * w + cx;
        float pcy = dy * h + cy;
        float pw  = expf(dw) * w;
        float ph  = expf(dh) * h;
        float x1 = pcx - 0.5f * pw;
        float y1 = pcy - 0.5f * ph;
        float x2 = (pcx + 0.5f * pw) - 1.0f;
        float y2 = (pcy + 0.5f * ph) - 1.0f;
        x1 = fminf(fmaxf(x1, 0.0f), IMW - 1.0f);
        y1 = fminf(fmaxf(y1, 0.0f), IMH - 1.0f);
        x2 = fminf(fmaxf(x2, 0.0f), IMW - 1.0f);
        y2 = fminf(fmaxf(y2, 0.0f), IMH - 1.0f);
        sbox[p] = make_float4(x1, y1, x2, y2);
        ssc[p]  = score;
        float key = (score > SCORE_T) ? -score : __int_as_float(0x7f800000);
        skey[p] = (((unsigned long long)fkey(key)) << 32) | (unsigned int)p;
    }
    __syncthreads();
    for (int k = 2; k <= P_N; k <<= 1) {
        for (int j = k >> 1; j > 0; j >>= 1) {
            for (int t = tid; t < P_N; t += 1024) {
                int ixj = t ^ j;
                if (ixj > t) {
                    unsigned long long a = skey[t], b = skey[ixj];
                    bool up = ((t & k) == 0);
                    if ((a > b) == up) { skey[t] = b; skey[ixj] = a; }
                }
            }
            __syncthreads();
        }
    }
    for (int e = tid; e < P_N; e += 1024) {
        unsigned long long kv = skey[e];
        int idx = (int)(kv & 0xFFFFFFFFull);
        float4 b4 = sbox[idx];
        float  s  = ssc[idx];
        float* o = out + ((size_t)img * P_N + e) * 5;
        o[0] = b4.x; o[1] = b4.y; o[2] = b4.z; o[3] = b4.w; o[4] = s;
    }
}

__global__ __launch_bounds__(64) void nms_fallback(float* __restrict__ out)
{
#pragma clang fp contract(off)
    __shared__ float4 sb[P_N];
    const int img  = blockIdx.x;
    const int lane = threadIdx.x;
    unsigned int keep = 0;
    for (int b = 0; b < 32; ++b) {
        int p = lane * 32 + b;
        const float* o = out + ((size_t)img * P_N + p) * 5;
        sb[p] = make_float4(o[0], o[1], o[2], o[3]);
        if (o[4] > SCORE_T) keep |= (1u << b);
    }
    __syncthreads();
    for (int i = 0; i < P_N; ++i) {
        unsigned int kw =
            (unsigned int)__builtin_amdgcn_readlane((int)keep, i >> 5);
        if ((kw >> (i & 31)) & 1u) {
            float4 bi = sb[i];
            float area_i = (bi.z - bi.x) * (bi.w - bi.y);
            unsigned int m = 0;
            for (int b = 0; b < 32; ++b) {
                int j = lane * 32 + b;
                if (j > i) {
                    float4 bj = sb[j];
                    float area_j = (bj.z - bj.x) * (bj.w - bj.y);
                    float ltx = fmaxf(bi.x, bj.x);
                    float lty = fmaxf(bi.y, bj.y);
                    float rbx = fminf(bi.z, bj.z);
                    float rby = fminf(bi.w, bj.w);
                    float wx = fmaxf(rbx - ltx, 0.0f);
                    float wy = fmaxf(rby - lty, 0.0f);
                    float inter = wx * wy;
                    float denom = ((area_i + area_j) - inter) + 1e-9f;
                    if ((inter / denom) > NMS_T) m |= (1u << b);
                }
            }
            keep &= ~m;
        }
    }
    for (int b = 0; b < 32; ++b) {
        if (!((keep >> b) & 1u)) {
            int p = lane * 32 + b;
            float* o = out + ((size_t)img * P_N + p) * 5;
            o[0] = 0.0f; o[1] = 0.0f; o[2] = 0.0f; o[3] = 0.0f; o[4] = 0.0f;
        }
    }
}

// ---------------------------------------------------------------------------
extern "C" void kernel_launch(void* const* d_in, const int* in_sizes, int n_in,
                              void* d_out, int out_size, void* d_ws, size_t ws_size,
                              hipStream_t stream) {
    const float* cls   = (const float*)d_in[0];
    const float* codes = (const float*)d_in[1];
    const float* props = (const float*)d_in[2];
    float* out = (float*)d_out;

    // ws layout
    const size_t off_boxes  = 0;                                      // 512 KB
    const size_t off_scores = off_boxes  + (size_t)B_IMG * P_N * 16;  // 128 KB
    const size_t off_keys   = off_scores + (size_t)B_IMG * P_N * 4;   // 128 KB
    const size_t off_tmask  = off_keys   + (size_t)B_IMG * P_N * 4;
    const size_t total      = off_tmask + (size_t)B_IMG * IMG_TM_U32 * 4; // +4.3 MB

    if (ws_size >= total) {
        float4*       boxes4 = (float4*)((char*)d_ws + off_boxes);
        float*        scores = (float*)((char*)d_ws + off_scores);
        unsigned int* keys   = (unsigned int*)((char*)d_ws + off_keys);
        unsigned int* tmask  = (unsigned int*)((char*)d_ws + off_tmask);

        decode_kernel<<<(B_IMG * P_N) / 256, 256, 0, stream>>>(
            cls, codes, props, boxes4, scores, keys);
        rank_kernel<<<B_IMG * 32, 512, 0, stream>>>(boxes4, scores, keys, out);
        tmask_kernel<<<B_IMG * 256, 512, 0, stream>>>(out, tmask);
        fixpoint_kernel<<<B_IMG, 512, 0, stream>>>(out, tmask);
    } else {
        prep_sort_kernel<<<B_IMG, 1024, 0, stream>>>(cls, codes, props, out);
        nms_fallback<<<B_IMG, 64, 0, stream>>>(out);
    }
}

// Round 7
// 98.503 us; speedup vs baseline: 5.2264x; 1.0798x over previous
//
#include <hip/hip_runtime.h>
#include <math.h>

#define B_IMG 16
#define P_N   2048
#define IMG_TM_U32 67584   // per-image triangular mask u32 words

constexpr float SCORE_T = 0.05f;
constexpr float XCLIP   = 4.135166556742356f; // log(1000/16)
constexpr float IMW     = 1333.0f;
constexpr float IMH     = 800.0f;

// monotone float->uint mapping (ascending float order, incl +inf)
__device__ __forceinline__ unsigned int fkey(float f) {
    unsigned int u = __float_as_uint(f);
    return (u & 0x80000000u) ? ~u : (u | 0x80000000u);
}

// u32 word offset of row j's mask within an image (compact triangular rows)
__device__ __forceinline__ unsigned int tm_base(int j) {
    int b = j >> 6, r = j & 63;
    return 2u * (unsigned)(b + 1) * (unsigned)(32 * b + r);
}

__device__ __forceinline__ void decode_row(
    const float* cls, const float* codes, const float* props, int gid,
    float4& box, float& score)
{
    float2 lg = reinterpret_cast<const float2*>(cls)[gid];
    score = 1.0f / (1.0f + expf(lg.x - lg.y));
    float4 pb = reinterpret_cast<const float4*>(props)[gid];
    float4 c  = reinterpret_cast<const float4*>(codes)[gid * 2 + 1];
    float w  = pb.z - pb.x + 1.0f;
    float h  = pb.w - pb.y + 1.0f;
    float cx = pb.x + 0.5f * w;
    float cy = pb.y + 0.5f * h;
    float dx = c.x / 10.0f;
    float dy = c.y / 10.0f;
    float dw = fminf(c.z / 5.0f, XCLIP);
    float dh = fminf(c.w / 5.0f, XCLIP);
    float pcx = dx * w + cx;
    float pcy = dy * h + cy;
    float pw  = expf(dw) * w;
    float ph  = expf(dh) * h;
    float x1 = pcx - 0.5f * pw;
    float y1 = pcy - 0.5f * ph;
    float x2 = (pcx + 0.5f * pw) - 1.0f;
    float y2 = (pcy + 0.5f * ph) - 1.0f;
    box.x = fminf(fmaxf(x1, 0.0f), IMW - 1.0f);
    box.y = fminf(fmaxf(y1, 0.0f), IMH - 1.0f);
    box.z = fminf(fmaxf(x2, 0.0f), IMW - 1.0f);
    box.w = fminf(fmaxf(y2, 0.0f), IMH - 1.0f);
}

// ---------------------------------------------------------------------------
// K1: fused key-gen + stable rank-by-counting + decode + scatter sorted rows
// ---------------------------------------------------------------------------
__global__ __launch_bounds__(512) void rank_kernel(
    const float* __restrict__ cls, const float* __restrict__ codes,
    const float* __restrict__ props, float* __restrict__ out)
{
#pragma clang fp contract(off)
    __shared__ unsigned int sk[P_N];
    __shared__ unsigned short pc[512];
    const int img = blockIdx.x >> 5;   // 32 blocks per image
    const int blk = blockIdx.x & 31;   // 64 rows per block
    const int tid = threadIdx.x;

    for (int p = tid; p < P_N; p += 512) {
        float2 lg = reinterpret_cast<const float2*>(cls)[img * P_N + p];
        float score = 1.0f / (1.0f + expf(lg.x - lg.y));
        float keyf = (score > SCORE_T) ? -score : __int_as_float(0x7f800000);
        sk[p] = fkey(keyf);
    }
    __syncthreads();

    const int il = tid >> 3, sub = tid & 7;      // 8 threads per row
    const int i  = blk * 64 + il;
    const unsigned int ki = sk[i];
    int cnt = 0;
    for (int t = 0; t < 256; ++t) {
        int j = sub + 8 * ((t + il) & 255);
        unsigned int kj = sk[j];
        cnt += (kj < ki) || (kj == ki && j < i);
    }
    pc[tid] = (unsigned short)cnt;
    __syncthreads();

    if (tid < 64) {
        const int i2 = blk * 64 + tid;
        int r = 0;
#pragma unroll
        for (int s = 0; s < 8; ++s) r += pc[tid * 8 + s];
        float4 b; float sc;
        decode_row(cls, codes, props, img * P_N + i2, b, sc);
        float* o = out + ((size_t)img * P_N + r) * 5;
        o[0] = b.x; o[1] = b.y; o[2] = b.z; o[3] = b.w; o[4] = sc;
    }
}

// ---------------------------------------------------------------------------
// K2: triangular mask, tile-transposed. One wave per (g,c) 64x64 tile:
//   lane = j within j-block g; uniform inner loop over i in i-block c.
//   Broadcast LDS reads, per-lane bit accumulate, no ballot, no division
//   (exact predicate: RN(inter/denom)>0.5 <=> inter > denom*(0.5+2^-25),
//    product exact in double; denom<=0 edge cases handled explicitly).
// ---------------------------------------------------------------------------
#define TM_WPB 4   // waves per block
__global__ __launch_bounds__(64 * TM_WPB) void tmask_kernel(
    const float* __restrict__ out, unsigned int* __restrict__ tmask)
{
#pragma clang fp contract(off)
    __shared__ float4 sbox[TM_WPB][64];
    __shared__ float  sarea[TM_WPB][64];
    const int tid  = threadIdx.x;
    const int wv   = tid >> 6;
    const int lane = tid & 63;

    const int W   = blockIdx.x * TM_WPB + wv;   // global wave id
    const int img = W / 528;
    int r = W - img * 528;
    int g = 0, acc = 0;
    while (acc + g + 1 <= r) { acc += g + 1; ++g; }
    const int c = r - acc;                      // 0 <= c <= g

    // stage i-block c (this wave's private LDS region)
    {
        const int irow = c * 64 + lane;
        const float* oi = out + ((size_t)img * P_N + irow) * 5;
        float4 bi = make_float4(oi[0], oi[1], oi[2], oi[3]);
        sbox[wv][lane]  = bi;
        sarea[wv][lane] = (bi.z - bi.x) * (bi.w - bi.y);
    }
    // per-lane j row
    const int jrow = g * 64 + lane;
    const float* oj = out + ((size_t)img * P_N + jrow) * 5;
    const float4 bj = make_float4(oj[0], oj[1], oj[2], oj[3]);
    const float  aj = (bj.z - bj.x) * (bj.w - bj.y);
    __syncthreads();

    const double C = 0x1.000001p-1;   // 0.5*(1+2^-24)
    unsigned int w0 = 0, w1 = 0;

#define IOU_BIT(T, DIAG, ACC, BITI)                                          \
    {                                                                        \
        float4 bi = sbox[wv][(T)];                                           \
        float  ai = sarea[wv][(T)];                                          \
        float ltx = fmaxf(bi.x, bj.x);                                       \
        float lty = fmaxf(bi.y, bj.y);                                       \
        float rbx = fminf(bi.z, bj.z);                                       \
        float rby = fminf(bi.w, bj.w);                                       \
        float wx = fmaxf(rbx - ltx, 0.0f);                                   \
        float wy = fmaxf(rby - lty, 0.0f);                                   \
        float inter = wx * wy;                                               \
        float denom = ((ai + aj) - inter) + 1e-9f;                           \
        bool sup = ((double)inter > (double)denom * C);                      \
        if (!(denom > 0.0f))                                                 \
            sup = (inter > 0.0f) && (__float_as_uint(denom) == 0u);          \
        if (DIAG) sup = sup && ((T) < lane);                                 \
        ACC |= sup ? (1u << (BITI)) : 0u;                                    \
    }

    if (c < g) {
#pragma unroll 16
        for (int t = 0; t < 32; ++t) IOU_BIT(t, false, w0, t)
#pragma unroll 16
        for (int t = 32; t < 64; ++t) IOU_BIT(t, false, w1, t - 32)
    } else {   // diagonal tile: need i < j
#pragma unroll 16
        for (int t = 0; t < 32; ++t) IOU_BIT(t, true, w0, t)
#pragma unroll 16
        for (int t = 32; t < 64; ++t) IOU_BIT(t, true, w1, t - 32)
    }
#undef IOU_BIT

    unsigned int base = (size_t)0 + tm_base(jrow);   // = 2(g+1)(32g+lane)
    unsigned int* dst = tmask + (size_t)img * IMG_TM_U32 + base + 2 * c;
    dst[0] = w0;
    dst[1] = w1;
}

// ---------------------------------------------------------------------------
// K3: Jacobi fixpoint of  k[j] = valid[j] & ~OR_{i<j,sup(i,j)} k[i]
//   (validated round 6: unique fixpoint == greedy NMS)
// ---------------------------------------------------------------------------
__global__ __launch_bounds__(512) void fixpoint_kernel(
    float* __restrict__ out, const unsigned int* __restrict__ tmask)
{
    __shared__ unsigned int kw[64];
    __shared__ int flag;
    const int img = blockIdx.x;
    const int tid = threadIdx.x;
    const int wv = tid >> 6, lane = tid & 63;

    const int g1 = wv, g2 = 15 - wv, g3 = 16 + wv, g4 = 31 - wv;
    const int j1 = g1 * 64 + lane, j2 = g2 * 64 + lane,
              j3 = g3 * 64 + lane, j4 = g4 * 64 + lane;
    const int n1 = 2 * (g1 + 1), n2 = 2 * (g2 + 1),
              n3 = 2 * (g3 + 1), n4 = 2 * (g4 + 1);

    const unsigned int* tmi = tmask + (size_t)img * IMG_TM_U32;
    unsigned int m1[16], m2[32], m3[48], m4[64];
    {
        const unsigned int* p1 = tmi + tm_base(j1);
#pragma unroll
        for (int w = 0; w < 16; ++w) m1[w] = (w < n1) ? p1[w] : 0u;
        const unsigned int* p2 = tmi + tm_base(j2);
#pragma unroll
        for (int w = 0; w < 32; ++w) m2[w] = (w < n2) ? p2[w] : 0u;
        const unsigned int* p3 = tmi + tm_base(j3);
#pragma unroll
        for (int w = 0; w < 48; ++w) m3[w] = (w < n3) ? p3[w] : 0u;
        const unsigned int* p4 = tmi + tm_base(j4);
#pragma unroll
        for (int w = 0; w < 64; ++w) m4[w] = (w < n4) ? p4[w] : 0u;
    }

    const bool v1 = out[((size_t)img * P_N + j1) * 5 + 4] > SCORE_T;
    const bool v2 = out[((size_t)img * P_N + j2) * 5 + 4] > SCORE_T;
    const bool v3 = out[((size_t)img * P_N + j3) * 5 + 4] > SCORE_T;
    const bool v4 = out[((size_t)img * P_N + j4) * 5 + 4] > SCORE_T;
    bool k1 = v1, k2 = v2, k3 = v3, k4 = v4;

    auto publish = [&](bool a, bool b, bool c, bool d) {
        unsigned long long t;
        t = __ballot(a);
        if (lane == 0) { kw[2*g1] = (unsigned int)t; kw[2*g1+1] = (unsigned int)(t>>32); }
        t = __ballot(b);
        if (lane == 0) { kw[2*g2] = (unsigned int)t; kw[2*g2+1] = (unsigned int)(t>>32); }
        t = __ballot(c);
        if (lane == 0) { kw[2*g3] = (unsigned int)t; kw[2*g3+1] = (unsigned int)(t>>32); }
        t = __ballot(d);
        if (lane == 0) { kw[2*g4] = (unsigned int)t; kw[2*g4+1] = (unsigned int)(t>>32); }
    };

    publish(k1, k2, k3, k4);
    __syncthreads();

    for (;;) {
        unsigned int s1 = 0, s2 = 0, s3 = 0, s4 = 0;
#pragma unroll
        for (int w = 0; w < 16; ++w) s1 |= m1[w] & kw[w];
#pragma unroll
        for (int w = 0; w < 32; ++w) s2 |= m2[w] & kw[w];
#pragma unroll
        for (int w = 0; w < 48; ++w) s3 |= m3[w] & kw[w];
#pragma unroll
        for (int w = 0; w < 64; ++w) s4 |= m4[w] & kw[w];
        bool nk1 = v1 && !s1, nk2 = v2 && !s2, nk3 = v3 && !s3, nk4 = v4 && !s4;
        bool ch = (nk1 != k1) | (nk2 != k2) | (nk3 != k3) | (nk4 != k4);

        __syncthreads();
        if (tid == 0) flag = 0;
        __syncthreads();
        publish(nk1, nk2, nk3, nk4);
        if (__builtin_amdgcn_ballot_w64(ch) != 0 && lane == 0) flag = 1;
        k1 = nk1; k2 = nk2; k3 = nk3; k4 = nk4;
        __syncthreads();
        if (!flag) break;
    }

    auto zero_row = [&](int j, bool k) {
        if (!k) {
            float* o = out + ((size_t)img * P_N + j) * 5;
            o[0] = 0.0f; o[1] = 0.0f; o[2] = 0.0f; o[3] = 0.0f; o[4] = 0.0f;
        }
    };
    zero_row(j1, k1); zero_row(j2, k2); zero_row(j3, k3); zero_row(j4, k4);
}

// ---------------------------------------------------------------------------
// ws-too-small fallback (validated rounds 1-4): bitonic sort + serial cascade
// ---------------------------------------------------------------------------
__global__ __launch_bounds__(1024) void prep_sort_kernel(
    const float* __restrict__ cls, const float* __restrict__ codes,
    const float* __restrict__ props, float* __restrict__ out)
{
#pragma clang fp contract(off)
    __shared__ float4 sbox[P_N];
    __shared__ float  ssc[P_N];
    __shared__ unsigned long long skey[P_N];
    const int img = blockIdx.x;
    const int tid = threadIdx.x;

    for (int p = tid; p < P_N; p += 1024) {
        float4 b; float sc;
        decode_row(cls, codes, props, img * P_N + p, b, sc);
        sbox[p] = b;
        ssc[p]  = sc;
        float key = (sc > SCORE_T) ? -sc : __int_as_float(0x7f800000);
        skey[p] = (((unsigned long long)fkey(key)) << 32) | (unsigned int)p;
    }
    __syncthreads();
    for (int k = 2; k <= P_N; k <<= 1) {
        for (int j = k >> 1; j > 0; j >>= 1) {
            for (int t = tid; t < P_N; t += 1024) {
                int ixj = t ^ j;
                if (ixj > t) {
                    unsigned long long a = skey[t], b = skey[ixj];
                    bool up = ((t & k) == 0);
                    if ((a > b) == up) { skey[t] = b; skey[ixj] = a; }
                }
            }
            __syncthreads();
        }
    }
    for (int e = tid; e < P_N; e += 1024) {
        unsigned long long kv = skey[e];
        int idx = (int)(kv & 0xFFFFFFFFull);
        float4 b4 = sbox[idx];
        float  s  = ssc[idx];
        float* o = out + ((size_t)img * P_N + e) * 5;
        o[0] = b4.x; o[1] = b4.y; o[2] = b4.z; o[3] = b4.w; o[4] = s;
    }
}

__global__ __launch_bounds__(64) void nms_fallback(float* __restrict__ out)
{
#pragma clang fp contract(off)
    __shared__ float4 sb[P_N];
    const int img  = blockIdx.x;
    const int lane = threadIdx.x;
    unsigned int keep = 0;
    for (int b = 0; b < 32; ++b) {
        int p = lane * 32 + b;
        const float* o = out + ((size_t)img * P_N + p) * 5;
        sb[p] = make_float4(o[0], o[1], o[2], o[3]);
        if (o[4] > SCORE_T) keep |= (1u << b);
    }
    __syncthreads();
    for (int i = 0; i < P_N; ++i) {
        unsigned int kw =
            (unsigned int)__builtin_amdgcn_readlane((int)keep, i >> 5);
        if ((kw >> (i & 31)) & 1u) {
            float4 bi = sb[i];
            float area_i = (bi.z - bi.x) * (bi.w - bi.y);
            unsigned int m = 0;
            for (int b = 0; b < 32; ++b) {
                int j = lane * 32 + b;
                if (j > i) {
                    float4 bj = sb[j];
                    float area_j = (bj.z - bj.x) * (bj.w - bj.y);
                    float ltx = fmaxf(bi.x, bj.x);
                    float lty = fmaxf(bi.y, bj.y);
                    float rbx = fminf(bi.z, bj.z);
                    float rby = fminf(bi.w, bj.w);
                    float wx = fmaxf(rbx - ltx, 0.0f);
                    float wy = fmaxf(rby - lty, 0.0f);
                    float inter = wx * wy;
                    float denom = ((area_i + area_j) - inter) + 1e-9f;
                    if ((inter / denom) > 0.5f) m |= (1u << b);
                }
            }
            keep &= ~m;
        }
    }
    for (int b = 0; b < 32; ++b) {
        if (!((keep >> b) & 1u)) {
            int p = lane * 32 + b;
            float* o = out + ((size_t)img * P_N + p) * 5;
            o[0] = 0.0f; o[1] = 0.0f; o[2] = 0.0f; o[3] = 0.0f; o[4] = 0.0f;
        }
    }
}

// ---------------------------------------------------------------------------
extern "C" void kernel_launch(void* const* d_in, const int* in_sizes, int n_in,
                              void* d_out, int out_size, void* d_ws, size_t ws_size,
                              hipStream_t stream) {
    const float* cls   = (const float*)d_in[0];
    const float* codes = (const float*)d_in[1];
    const float* props = (const float*)d_in[2];
    float* out = (float*)d_out;

    const size_t tmask_bytes = (size_t)B_IMG * IMG_TM_U32 * 4;   // 4.3 MB

    if (ws_size >= tmask_bytes) {
        unsigned int* tmask = (unsigned int*)d_ws;
        rank_kernel<<<B_IMG * 32, 512, 0, stream>>>(cls, codes, props, out);
        tmask_kernel<<<(B_IMG * 528) / TM_WPB, 64 * TM_WPB, 0, stream>>>(out, tmask);
        fixpoint_kernel<<<B_IMG, 512, 0, stream>>>(out, tmask);
    } else {
        prep_sort_kernel<<<B_IMG, 1024, 0, stream>>>(cls, codes, props, out);
        nms_fallback<<<B_IMG, 64, 0, stream>>>(out);
    }
}

// Round 8
// 78.889 us; speedup vs baseline: 6.5258x; 1.2486x over previous
//
#include <hip/hip_runtime.h>
#include <math.h>

#define B_IMG 16
#define P_N   2048
#define IMG_TM_U32 69632   // per-image padded triangular mask u32 words

constexpr float SCORE_T = 0.05f;
constexpr float XCLIP   = 4.135166556742356f; // log(1000/16)
constexpr float IMW     = 1333.0f;
constexpr float IMH     = 800.0f;

// monotone float->uint mapping (ascending float order, incl +inf)
__device__ __forceinline__ unsigned int fkey(float f) {
    unsigned int u = __float_as_uint(f);
    return (u & 0x80000000u) ? ~u : (u | 0x80000000u);
}

// Padded triangular layout: block b rows have RW(b)=4*((b>>1)+1) u32 words,
// 16B-aligned. Block start S(b) = 256*T(b), T(b) = (b&1)?(q+1)^2 : q(q+1).
__device__ __forceinline__ unsigned int row_base(int j) {
    int b = j >> 6, r = j & 63;
    int q = b >> 1;
    int T = (b & 1) ? (q + 1) * (q + 1) : q * (q + 1);
    int RW = 4 * (q + 1);
    return 256u * (unsigned)T + (unsigned)(r * RW);
}

__device__ __forceinline__ void decode_row(
    const float* cls, const float* codes, const float* props, int gid,
    float4& box, float& score)
{
    float2 lg = reinterpret_cast<const float2*>(cls)[gid];
    score = 1.0f / (1.0f + expf(lg.x - lg.y));
    float4 pb = reinterpret_cast<const float4*>(props)[gid];
    float4 c  = reinterpret_cast<const float4*>(codes)[gid * 2 + 1];
    float w  = pb.z - pb.x + 1.0f;
    float h  = pb.w - pb.y + 1.0f;
    float cx = pb.x + 0.5f * w;
    float cy = pb.y + 0.5f * h;
    float dx = c.x / 10.0f;
    float dy = c.y / 10.0f;
    float dw = fminf(c.z / 5.0f, XCLIP);
    float dh = fminf(c.w / 5.0f, XCLIP);
    float pcx = dx * w + cx;
    float pcy = dy * h + cy;
    float pw  = expf(dw) * w;
    float ph  = expf(dh) * h;
    float x1 = pcx - 0.5f * pw;
    float y1 = pcy - 0.5f * ph;
    float x2 = (pcx + 0.5f * pw) - 1.0f;
    float y2 = (pcy + 0.5f * ph) - 1.0f;
    box.x = fminf(fmaxf(x1, 0.0f), IMW - 1.0f);
    box.y = fminf(fmaxf(y1, 0.0f), IMH - 1.0f);
    box.z = fminf(fmaxf(x2, 0.0f), IMW - 1.0f);
    box.w = fminf(fmaxf(y2, 0.0f), IMH - 1.0f);
}

// ---------------------------------------------------------------------------
// K1: fused key-gen + stable rank-by-counting + decode + scatter sorted rows
// ---------------------------------------------------------------------------
__global__ __launch_bounds__(512) void rank_kernel(
    const float* __restrict__ cls, const float* __restrict__ codes,
    const float* __restrict__ props, float* __restrict__ out)
{
#pragma clang fp contract(off)
    __shared__ unsigned int sk[P_N];
    __shared__ unsigned short pc[512];
    const int img = blockIdx.x >> 5;   // 32 blocks per image
    const int blk = blockIdx.x & 31;   // 64 rows per block
    const int tid = threadIdx.x;

    for (int p = tid; p < P_N; p += 512) {
        float2 lg = reinterpret_cast<const float2*>(cls)[img * P_N + p];
        float score = 1.0f / (1.0f + expf(lg.x - lg.y));
        float keyf = (score > SCORE_T) ? -score : __int_as_float(0x7f800000);
        sk[p] = fkey(keyf);
    }
    __syncthreads();

    const int il = tid >> 3, sub = tid & 7;      // 8 threads per row
    const int i  = blk * 64 + il;
    const unsigned int ki = sk[i];
    int cnt = 0;
    for (int t = 0; t < 256; ++t) {
        int j = sub + 8 * ((t + il) & 255);
        unsigned int kj = sk[j];
        cnt += (kj < ki) || (kj == ki && j < i);
    }
    pc[tid] = (unsigned short)cnt;
    __syncthreads();

    if (tid < 64) {
        const int i2 = blk * 64 + tid;
        int r = 0;
#pragma unroll
        for (int s = 0; s < 8; ++s) r += pc[tid * 8 + s];
        float4 b; float sc;
        decode_row(cls, codes, props, img * P_N + i2, b, sc);
        float* o = out + ((size_t)img * P_N + r) * 5;
        o[0] = b.x; o[1] = b.y; o[2] = b.z; o[3] = b.w; o[4] = sc;
    }
}

// ---------------------------------------------------------------------------
// K2: triangular mask, tile-transposed (validated round 7). One wave per
//   (g,c) 64x64 tile: lane = j in block g, uniform inner loop over i-block c.
//   Exact no-division predicate; writes uint2 into padded layout.
// ---------------------------------------------------------------------------
#define TM_WPB 4   // waves per block
__global__ __launch_bounds__(64 * TM_WPB) void tmask_kernel(
    const float* __restrict__ out, unsigned int* __restrict__ tmask)
{
#pragma clang fp contract(off)
    __shared__ float4 sbox[TM_WPB][64];
    __shared__ float  sarea[TM_WPB][64];
    const int tid  = threadIdx.x;
    const int wv   = tid >> 6;
    const int lane = tid & 63;

    const int W   = blockIdx.x * TM_WPB + wv;   // global wave id
    const int img = W / 528;
    int r = W - img * 528;
    int g = 0, acc = 0;
    while (acc + g + 1 <= r) { acc += g + 1; ++g; }
    const int c = r - acc;                      // 0 <= c <= g

    // stage i-block c (this wave's private LDS region)
    {
        const int irow = c * 64 + lane;
        const float* oi = out + ((size_t)img * P_N + irow) * 5;
        float4 bi = make_float4(oi[0], oi[1], oi[2], oi[3]);
        sbox[wv][lane]  = bi;
        sarea[wv][lane] = (bi.z - bi.x) * (bi.w - bi.y);
    }
    // per-lane j row
    const int jrow = g * 64 + lane;
    const float* oj = out + ((size_t)img * P_N + jrow) * 5;
    const float4 bj = make_float4(oj[0], oj[1], oj[2], oj[3]);
    const float  aj = (bj.z - bj.x) * (bj.w - bj.y);
    __syncthreads();

    const double C = 0x1.000001p-1;   // 0.5*(1+2^-24)
    unsigned int w0 = 0, w1 = 0;

#define IOU_BIT(T, DIAG, ACC, BITI)                                          \
    {                                                                        \
        float4 bi = sbox[wv][(T)];                                           \
        float  ai = sarea[wv][(T)];                                          \
        float ltx = fmaxf(bi.x, bj.x);                                       \
        float lty = fmaxf(bi.y, bj.y);                                       \
        float rbx = fminf(bi.z, bj.z);                                       \
        float rby = fminf(bi.w, bj.w);                                       \
        float wx = fmaxf(rbx - ltx, 0.0f);                                   \
        float wy = fmaxf(rby - lty, 0.0f);                                   \
        float inter = wx * wy;                                               \
        float denom = ((ai + aj) - inter) + 1e-9f;                           \
        bool sup = ((double)inter > (double)denom * C);                      \
        if (!(denom > 0.0f))                                                 \
            sup = (inter > 0.0f) && (__float_as_uint(denom) == 0u);          \
        if (DIAG) sup = sup && ((T) < lane);                                 \
        ACC |= sup ? (1u << (BITI)) : 0u;                                    \
    }

    if (c < g) {
#pragma unroll 16
        for (int t = 0; t < 32; ++t) IOU_BIT(t, false, w0, t)
#pragma unroll 16
        for (int t = 32; t < 64; ++t) IOU_BIT(t, false, w1, t - 32)
    } else {   // diagonal tile: need i < j
#pragma unroll 16
        for (int t = 0; t < 32; ++t) IOU_BIT(t, true, w0, t)
#pragma unroll 16
        for (int t = 32; t < 64; ++t) IOU_BIT(t, true, w1, t - 32)
    }
#undef IOU_BIT

    unsigned int* dst = tmask + (size_t)img * IMG_TM_U32 + row_base(jrow) + 2 * c;
    *reinterpret_cast<uint2*>(dst) = make_uint2(w0, w1);
}

// ---------------------------------------------------------------------------
// K3: Jacobi fixpoint, register-exact. 1024 thr/image, 2 rows/thread with
//   pairing (g, 31-g): every thread holds exactly 17 uint4 of mask. All row
//   geometry compile-time via fp_body<G1,G2> (no predication, no spills).
// ---------------------------------------------------------------------------
template<int G>
struct RowMask {
    static constexpr int Q  = G >> 1;
    static constexpr int NV = Q + 1;                 // uint4 count = RW/4
    static constexpr int NW = 2 * (G + 1);           // valid words
    static constexpr int RW = 4 * NV;
    static constexpr int TT = (G & 1) ? (Q + 1) * (Q + 1) : Q * (Q + 1);
    static constexpr int S  = 256 * TT;              // block start (words)
    uint4 m[NV];
    __device__ __forceinline__ void load(const unsigned int* tmi, int lane) {
        const uint4* p = reinterpret_cast<const uint4*>(tmi + S + lane * RW);
#pragma unroll
        for (int v = 0; v < NV; ++v) m[v] = p[v];
        if constexpr (NW < RW) {   // even G: padding words never written
            m[NV - 1].z = 0u; m[NV - 1].w = 0u;
        }
    }
    __device__ __forceinline__ unsigned int andor(const unsigned int* kw) const {
        const uint4* kw4 = reinterpret_cast<const uint4*>(kw);
        unsigned int s = 0;
#pragma unroll
        for (int v = 0; v < NV; ++v) {
            uint4 K = kw4[v];
            s |= m[v].x & K.x;
            s |= m[v].y & K.y;
            s |= m[v].z & K.z;
            s |= m[v].w & K.w;
        }
        return s;
    }
};

template<int G1, int G2>
__device__ __forceinline__ void fp_body(
    float* __restrict__ out, const unsigned int* __restrict__ tmi,
    int img, int lane, unsigned int* kw, int* flag)
{
    RowMask<G1> M1; RowMask<G2> M2;
    M1.load(tmi, lane);
    M2.load(tmi, lane);
    const int j1 = G1 * 64 + lane, j2 = G2 * 64 + lane;
    const bool v1 = out[((size_t)img * P_N + j1) * 5 + 4] > SCORE_T;
    const bool v2 = out[((size_t)img * P_N + j2) * 5 + 4] > SCORE_T;
    bool k1 = v1, k2 = v2;

    auto publish = [&](bool a, bool b) {
        unsigned long long t = __ballot(a);
        if (lane == 0) { kw[2*G1] = (unsigned int)t; kw[2*G1+1] = (unsigned int)(t >> 32); }
        t = __ballot(b);
        if (lane == 0) { kw[2*G2] = (unsigned int)t; kw[2*G2+1] = (unsigned int)(t >> 32); }
    };

    publish(k1, k2);
    __syncthreads();

    for (;;) {
        unsigned int s1 = M1.andor(kw);
        unsigned int s2 = M2.andor(kw);
        bool nk1 = v1 && (s1 == 0u);
        bool nk2 = v2 && (s2 == 0u);
        bool ch = (nk1 != k1) | (nk2 != k2);
        __syncthreads();                 // (1) kw reads done
        if constexpr (G1 == 0) { if (lane == 0) *flag = 0; }
        __syncthreads();                 // (2) reset visible
        publish(nk1, nk2);
        if (__builtin_amdgcn_ballot_w64(ch) != 0 && lane == 0) *flag = 1;
        k1 = nk1; k2 = nk2;
        __syncthreads();                 // (3) new kw + flag visible
        if (!*flag) break;
    }

    if (!k1) { float* o = out + ((size_t)img * P_N + j1) * 5;
        o[0] = 0.0f; o[1] = 0.0f; o[2] = 0.0f; o[3] = 0.0f; o[4] = 0.0f; }
    if (!k2) { float* o = out + ((size_t)img * P_N + j2) * 5;
        o[0] = 0.0f; o[1] = 0.0f; o[2] = 0.0f; o[3] = 0.0f; o[4] = 0.0f; }
}

__global__ __launch_bounds__(1024) void fixpoint_kernel(
    float* __restrict__ out, const unsigned int* __restrict__ tmask)
{
    __shared__ __align__(16) unsigned int kw[64];
    __shared__ int flag;
    const int img = blockIdx.x, tid = threadIdx.x;
    const int wv = tid >> 6, lane = tid & 63;
    const unsigned int* tmi = tmask + (size_t)img * IMG_TM_U32;
    switch (wv) {
        case  0: fp_body< 0, 31>(out, tmi, img, lane, kw, &flag); break;
        case  1: fp_body< 1, 30>(out, tmi, img, lane, kw, &flag); break;
        case  2: fp_body< 2, 29>(out, tmi, img, lane, kw, &flag); break;
        case  3: fp_body< 3, 28>(out, tmi, img, lane, kw, &flag); break;
        case  4: fp_body< 4, 27>(out, tmi, img, lane, kw, &flag); break;
        case  5: fp_body< 5, 26>(out, tmi, img, lane, kw, &flag); break;
        case  6: fp_body< 6, 25>(out, tmi, img, lane, kw, &flag); break;
        case  7: fp_body< 7, 24>(out, tmi, img, lane, kw, &flag); break;
        case  8: fp_body< 8, 23>(out, tmi, img, lane, kw, &flag); break;
        case  9: fp_body< 9, 22>(out, tmi, img, lane, kw, &flag); break;
        case 10: fp_body<10, 21>(out, tmi, img, lane, kw, &flag); break;
        case 11: fp_body<11, 20>(out, tmi, img, lane, kw, &flag); break;
        case 12: fp_body<12, 19>(out, tmi, img, lane, kw, &flag); break;
        case 13: fp_body<13, 18>(out, tmi, img, lane, kw, &flag); break;
        case 14: fp_body<14, 17>(out, tmi, img, lane, kw, &flag); break;
        case 15: fp_body<15, 16>(out, tmi, img, lane, kw, &flag); break;
    }
}

// ---------------------------------------------------------------------------
// ws-too-small fallback (validated rounds 1-4): bitonic sort + serial cascade
// ---------------------------------------------------------------------------
__global__ __launch_bounds__(1024) void prep_sort_kernel(
    const float* __restrict__ cls, const float* __restrict__ codes,
    const float* __restrict__ props, float* __restrict__ out)
{
#pragma clang fp contract(off)
    __shared__ float4 sbox[P_N];
    __shared__ float  ssc[P_N];
    __shared__ unsigned long long skey[P_N];
    const int img = blockIdx.x;
    const int tid = threadIdx.x;

    for (int p = tid; p < P_N; p += 1024) {
        float4 b; float sc;
        decode_row(cls, codes, props, img * P_N + p, b, sc);
        sbox[p] = b;
        ssc[p]  = sc;
        float key = (sc > SCORE_T) ? -sc : __int_as_float(0x7f800000);
        skey[p] = (((unsigned long long)fkey(key)) << 32) | (unsigned int)p;
    }
    __syncthreads();
    for (int k = 2; k <= P_N; k <<= 1) {
        for (int j = k >> 1; j > 0; j >>= 1) {
            for (int t = tid; t < P_N; t += 1024) {
                int ixj = t ^ j;
                if (ixj > t) {
                    unsigned long long a = skey[t], b = skey[ixj];
                    bool up = ((t & k) == 0);
                    if ((a > b) == up) { skey[t] = b; skey[ixj] = a; }
                }
            }
            __syncthreads();
        }
    }
    for (int e = tid; e < P_N; e += 1024) {
        unsigned long long kv = skey[e];
        int idx = (int)(kv & 0xFFFFFFFFull);
        float4 b4 = sbox[idx];
        float  s  = ssc[idx];
        float* o = out + ((size_t)img * P_N + e) * 5;
        o[0] = b4.x; o[1] = b4.y; o[2] = b4.z; o[3] = b4.w; o[4] = s;
    }
}

__global__ __launch_bounds__(64) void nms_fallback(float* __restrict__ out)
{
#pragma clang fp contract(off)
    __shared__ float4 sb[P_N];
    const int img  = blockIdx.x;
    const int lane = threadIdx.x;
    unsigned int keep = 0;
    for (int b = 0; b < 32; ++b) {
        int p = lane * 32 + b;
        const float* o = out + ((size_t)img * P_N + p) * 5;
        sb[p] = make_float4(o[0], o[1], o[2], o[3]);
        if (o[4] > SCORE_T) keep |= (1u << b);
    }
    __syncthreads();
    for (int i = 0; i < P_N; ++i) {
        unsigned int kw =
            (unsigned int)__builtin_amdgcn_readlane((int)keep, i >> 5);
        if ((kw >> (i & 31)) & 1u) {
            float4 bi = sb[i];
            float area_i = (bi.z - bi.x) * (bi.w - bi.y);
            unsigned int m = 0;
            for (int b = 0; b < 32; ++b) {
                int j = lane * 32 + b;
                if (j > i) {
                    float4 bj = sb[j];
                    float area_j = (bj.z - bj.x) * (bj.w - bj.y);
                    float ltx = fmaxf(bi.x, bj.x);
                    float lty = fmaxf(bi.y, bj.y);
                    float rbx = fminf(bi.z, bj.z);
                    float rby = fminf(bi.w, bj.w);
                    float wx = fmaxf(rbx - ltx, 0.0f);
                    float wy = fmaxf(rby - lty, 0.0f);
                    float inter = wx * wy;
                    float denom = ((area_i + area_j) - inter) + 1e-9f;
                    if ((inter / denom) > 0.5f) m |= (1u << b);
                }
            }
            keep &= ~m;
        }
    }
    for (int b = 0; b < 32; ++b) {
        if (!((keep >> b) & 1u)) {
            int p = lane * 32 + b;
            float* o = out + ((size_t)img * P_N + p) * 5;
            o[0] = 0.0f; o[1] = 0.0f; o[2] = 0.0f; o[3] = 0.0f; o[4] = 0.0f;
        }
    }
}

// ---------------------------------------------------------------------------
extern "C" void kernel_launch(void* const* d_in, const int* in_sizes, int n_in,
                              void* d_out, int out_size, void* d_ws, size_t ws_size,
                              hipStream_t stream) {
    const float* cls   = (const float*)d_in[0];
    const float* codes = (const float*)d_in[1];
    const float* props = (const float*)d_in[2];
    float* out = (float*)d_out;

    const size_t tmask_bytes = (size_t)B_IMG * IMG_TM_U32 * 4;   // 4.46 MB

    if (ws_size >= tmask_bytes) {
        unsigned int* tmask = (unsigned int*)d_ws;
        rank_kernel<<<B_IMG * 32, 512, 0, stream>>>(cls, codes, props, out);
        tmask_kernel<<<(B_IMG * 528) / TM_WPB, 64 * TM_WPB, 0, stream>>>(out, tmask);
        fixpoint_kernel<<<B_IMG, 1024, 0, stream>>>(out, tmask);
    } else {
        prep_sort_kernel<<<B_IMG, 1024, 0, stream>>>(cls, codes, props, out);
        nms_fallback<<<B_IMG, 64, 0, stream>>>(out);
    }
}